// Round 6
// baseline (1041.039 us; speedup 1.0000x reference)
//
#include <hip/hip_runtime.h>
#include <stdint.h>

#define T_DIM 512
#define B_DIM 256
#define OBS_DIM 128
#define H_DIM 256
#define TB (T_DIM * B_DIM)

typedef _Float16 f16;
typedef __attribute__((ext_vector_type(8))) _Float16 f16x8;
typedef __attribute__((ext_vector_type(4))) float f32x4;

union H2U { f16 h[2]; uint32_t u; };

__device__ __forceinline__ f32x4 fz4() { f32x4 v; v[0]=0.f; v[1]=0.f; v[2]=0.f; v[3]=0.f; return v; }
__device__ __forceinline__ float sigm(float x) {
  float e = __expf(-x);
  return __builtin_amdgcn_rcpf(1.f + e);
}
__device__ __forceinline__ float tanh_f(float x) {
  float e = __expf(-2.f * x);
  return (1.f - e) * __builtin_amdgcn_rcpf(1.f + e);
}

// ---------------------------------------------------------------------------
// K0: weights -> f16. encW 32768 | Wih 196608 | head 8192 (rows0-15 pol,16 val)
// ---------------------------------------------------------------------------
__global__ void k_prep(const float* __restrict__ encW, const float* __restrict__ Wih,
                       const float* __restrict__ polW, const float* __restrict__ valW,
                       f16* __restrict__ encW_h, f16* __restrict__ Wih_h,
                       f16* __restrict__ headW_h) {
  int e = blockIdx.x * 256 + threadIdx.x;
  if (e < 32768) { encW_h[e] = (f16)encW[e]; return; }
  e -= 32768;
  if (e < 196608) { Wih_h[e] = (f16)Wih[e]; return; }
  e -= 196608;
  if (e < 8192) {
    int r = e >> 8, c = e & 255;
    float v = (r < 16) ? polW[r * 256 + c] : (r == 16 ? valW[c] : 0.f);
    headW_h[e] = (f16)v;
  }
}

// ---------------------------------------------------------------------------
// K1: x = tanh(obs @ enc_W^T + enc_b) -> f16 into xgi. M-tile 128, grid 1024.
// ---------------------------------------------------------------------------
__global__ __launch_bounds__(512) void k_enc(const float* __restrict__ obs,
                                             const f16* __restrict__ encW_h,
                                             const float* __restrict__ enc_b,
                                             f16* __restrict__ xgi) {
  __shared__ f16 lA[128 * 64];  // 16KB [128 rows][64 k] swizzled
  __shared__ f16 lB[256 * 64];  // 32KB [256 n][64 k] swizzled
  const int tid = threadIdx.x, lane = tid & 63, w = tid >> 6;
  const int m0 = blockIdx.x * 128;
  f32x4 acc[16];
#pragma unroll
  for (int i = 0; i < 16; i++) acc[i] = fz4();

  for (int kc = 0; kc < 2; kc++) {
    const int k0c = kc * 64;
#pragma unroll
    for (int i = 0; i < 4; i++) {
      int c = tid + i * 512;
      int r = c >> 4, kk = (c & 15) * 4;
      float4 v = *(const float4*)(obs + (size_t)(m0 + r) * OBS_DIM + k0c + kk);
      H2U a, b;
      a.h[0] = (f16)v.x; a.h[1] = (f16)v.y; b.h[0] = (f16)v.z; b.h[1] = (f16)v.w;
      uint32_t off = ((uint32_t)(r * 128 + kk * 2)) ^ (((uint32_t)(r & 7)) << 4);
      uint2 p; p.x = a.u; p.y = b.u;
      *(uint2*)((char*)lA + off) = p;
    }
#pragma unroll
    for (int i = 0; i < 4; i++) {
      int c = tid + i * 512;
      int r = c >> 3, kk = (c & 7) * 8;
      f16x8 v = *(const f16x8*)(encW_h + (size_t)r * OBS_DIM + k0c + kk);
      uint32_t off = ((uint32_t)(r * 128 + kk * 2)) ^ (((uint32_t)(r & 7)) << 4);
      *(f16x8*)((char*)lB + off) = v;
    }
    __syncthreads();
#pragma unroll
    for (int ks = 0; ks < 2; ks++) {
      const int ar = w * 16 + (lane & 15);
      const int kofs = (ks * 32 + ((lane >> 4) << 3)) * 2;
      uint32_t aoff = ((uint32_t)(ar * 128 + kofs)) ^ (((uint32_t)(ar & 7)) << 4);
      f16x8 af = *(const f16x8*)((char*)lA + aoff);
#pragma unroll
      for (int i = 0; i < 16; i++) {
        const int br = i * 16 + (lane & 15);
        uint32_t boff = ((uint32_t)(br * 128 + kofs)) ^ (((uint32_t)(br & 7)) << 4);
        f16x8 bfr = *(const f16x8*)((char*)lB + boff);
        acc[i] = __builtin_amdgcn_mfma_f32_16x16x32_f16(af, bfr, acc[i], 0, 0, 0);
      }
    }
    __syncthreads();
  }
  const int mrow = m0 + w * 16 + ((lane >> 4) << 2);
#pragma unroll
  for (int i = 0; i < 16; i++) {
    const int col = i * 16 + (lane & 15);
    const float bb = enc_b[col];
#pragma unroll
    for (int r = 0; r < 4; r++) {
      float s = acc[i][r] + bb;
      xgi[(size_t)(mrow + r) * H_DIM + col] = (f16)tanh_f(s);
    }
  }
}

// ---------------------------------------------------------------------------
// K2: all 3 gates fused: gi = x @ W_ih^T + bias. M-tile 64, N=768, grid 2048.
// bias: b_ih + b_hh for r,z cols (<512); b_ih only for n.
// r,z -> gi_rz f16 [TB][256][2] INTERLEAVED; n -> xgi [TB][256].
// ---------------------------------------------------------------------------
__global__ __launch_bounds__(512) void k_gi3(const f16* __restrict__ xgi_r,
                                             const f16* __restrict__ Wih_h,
                                             const float* __restrict__ b_ih,
                                             const float* __restrict__ b_hh,
                                             f16* __restrict__ gi_rz,
                                             f16* __restrict__ xgi_w) {
  __shared__ f16 lA[64 * 64];    // 8KB
  __shared__ f16 lB[768 * 64];   // 96KB
  const int tid = threadIdx.x, lane = tid & 63, w = tid >> 6;
  const int m0 = blockIdx.x * 64;
  const int mstrip = w >> 1, nh = w & 1;
  f32x4 acc[24];
#pragma unroll
  for (int i = 0; i < 24; i++) acc[i] = fz4();

  for (int kc = 0; kc < 4; kc++) {
    const int k0c = kc * 64;
    {
      int r = tid >> 3, kk = (tid & 7) * 8;
      f16x8 v = *(const f16x8*)(xgi_r + (size_t)(m0 + r) * H_DIM + k0c + kk);
      uint32_t off = ((uint32_t)(r * 128 + kk * 2)) ^ (((uint32_t)(r & 7)) << 4);
      *(f16x8*)((char*)lA + off) = v;
    }
#pragma unroll
    for (int i = 0; i < 12; i++) {
      int c = tid + i * 512;
      int r = c >> 3, kk = (c & 7) * 8;
      f16x8 v = *(const f16x8*)(Wih_h + (size_t)r * H_DIM + k0c + kk);
      uint32_t off = ((uint32_t)(r * 128 + kk * 2)) ^ (((uint32_t)(r & 7)) << 4);
      *(f16x8*)((char*)lB + off) = v;
    }
    __syncthreads();
#pragma unroll
    for (int ks = 0; ks < 2; ks++) {
      const int ar = mstrip * 16 + (lane & 15);
      const int kofs = (ks * 32 + ((lane >> 4) << 3)) * 2;
      uint32_t aoff = ((uint32_t)(ar * 128 + kofs)) ^ (((uint32_t)(ar & 7)) << 4);
      f16x8 af = *(const f16x8*)((char*)lA + aoff);
#pragma unroll
      for (int i = 0; i < 24; i++) {
        const int br = nh * 384 + i * 16 + (lane & 15);
        uint32_t boff = ((uint32_t)(br * 128 + kofs)) ^ (((uint32_t)(br & 7)) << 4);
        f16x8 bfr = *(const f16x8*)((char*)lB + boff);
        acc[i] = __builtin_amdgcn_mfma_f32_16x16x32_f16(af, bfr, acc[i], 0, 0, 0);
      }
    }
    __syncthreads();
  }
  const int mrow = m0 + mstrip * 16 + ((lane >> 4) << 2);
#pragma unroll
  for (int i = 0; i < 24; i++) {
    const int col = nh * 384 + i * 16 + (lane & 15);
    float bb = b_ih[col];
    if (col < 512) bb += b_hh[col];
#pragma unroll
    for (int r = 0; r < 4; r++) {
      float s = acc[i][r] + bb;
      size_t tb = (size_t)(mrow + r);
      if (col < 512) gi_rz[tb * 512 + (size_t)((col & 255) * 2 + (col >> 8))] = (f16)s;
      else           xgi_w[tb * 256 + (col - 512)] = (f16)s;
    }
  }
}

// ---------------------------------------------------------------------------
// K3: GRU scan v6. grid(128) x block 256 (4 waves, 1 wave/SIMD), WG owns 2
// batch rows. KEY CHANGES vs v5 (LDS-pipe-bound diagnosis):
//  - 512-VGPR budget -> ALL 96 W_hh B-frags register-resident (384 VGPR).
//    No weight LDS reads at all.
//  - h stored as 2 real rows + 1 zero row; lanes with (lane&15)>=2 read the
//    zero row via per-lane constant base -> A-frag reads are same-address
//    broadcasts (near-free) instead of 64 conflicted ds_read_b128 per CU.
//  - wave owns 64 cols of ALL 3 gates -> redistribution stays wave-local;
//    2 h-outputs per lane; b_hh(n) as one scalar in phase B.
//  - gi prefetch distance 2 (no TLP at 1 wave/SIMD to hide HBM latency).
// ---------------------------------------------------------------------------
__global__ __launch_bounds__(256, 1) void k_scan(const float* __restrict__ Whh,
                                                 const float* __restrict__ b_hh,
                                                 const float* __restrict__ done,
                                                 const uint32_t* __restrict__ gi_rz,
                                                 f16* xgi) {
  __shared__ f16 h2[2][2][264];        // 2.06KB [buf][row][k]
  __shared__ f16 hz[264];              // zero row
  __shared__ float gh_l[4][3][64][2];  // 6KB [wave][g][col-in-slice][row]
  __shared__ float done_l[T_DIM][2];   // 4KB
  const int tid = threadIdx.x, lane = tid & 63, w = tid >> 6;
  const int b0 = blockIdx.x * 2;

  for (int i = tid; i < 2 * 2 * 264; i += 256) ((f16*)h2)[i] = (f16)0.f;
  for (int i = tid; i < 264; i += 256) hz[i] = (f16)0.f;
  for (int i = tid; i < T_DIM; i += 256) {
    float2 dv = *(const float2*)(done + (size_t)i * B_DIM + b0);
    done_l[i][0] = dv.x; done_l[i][1] = dv.y;
  }

  // W_hh -> 96 register-resident f16 B-frags. Wave w owns cols [w*64,w*64+64)
  // of each gate g: tile (g,j) = W rows g*256 + w*64 + j*16 + (lane&15).
  f16x8 wf[3][4][8];
#pragma unroll
  for (int g = 0; g < 3; g++) {
#pragma unroll
    for (int j = 0; j < 4; j++) {
      const int rowW = g * 256 + w * 64 + j * 16 + (lane & 15);
      const float* wrow = Whh + (size_t)rowW * H_DIM;
#pragma unroll
      for (int ks = 0; ks < 8; ks++) {
        const int k0 = ks * 32 + ((lane >> 4) << 3);
        float4 a = *(const float4*)(wrow + k0);
        float4 b = *(const float4*)(wrow + k0 + 4);
        f16x8 f;
        f[0] = (f16)a.x; f[1] = (f16)a.y; f[2] = (f16)a.z; f[3] = (f16)a.w;
        f[4] = (f16)b.x; f[5] = (f16)b.y; f[6] = (f16)b.z; f[7] = (f16)b.w;
        wf[g][j][ks] = f;
      }
    }
  }
  f32x4 zs = fz4();

  const int row_sel = lane & 15;
  const int koff = (lane >> 4) << 3;
  const f16* hA = (row_sel < 2) ? &h2[0][row_sel][koff] : &hz[koff];
  const f16* hB = (row_sel < 2) ? &h2[1][row_sel][koff] : &hz[koff];

  const int col = w * 64 + lane;
  const float bhhn = b_hh[512 + col];
  const uint32_t* prz = gi_rz + (size_t)b0 * 256 + col;
  const f16* pgn = xgi + (size_t)b0 * 256 + col;
  f16* pst = xgi + (size_t)b0 * 256 + col;

  // prefetch gi for t=0 and t=1
  uint2 rzA, rzB;
  f16 gnA0, gnA1, gnB0, gnB1;
  rzA.x = prz[0]; rzA.y = prz[256]; gnA0 = pgn[0]; gnA1 = pgn[256];
  prz += 65536; pgn += 65536;
  rzB.x = prz[0]; rzB.y = prz[256]; gnB0 = pgn[0]; gnB1 = pgn[256];
  prz += 65536; pgn += 65536;

  float hr0 = 0.f, hr1 = 0.f;
  __syncthreads();

#pragma unroll 2
  for (int t = 0; t < T_DIM; t++) {
    // issue prefetch for t+2 (consumed 2 full steps later)
    uint2 rzC; f16 gnC0, gnC1;
    if (t + 2 < T_DIM) {
      rzC.x = prz[0]; rzC.y = prz[256]; gnC0 = pgn[0]; gnC1 = pgn[256];
      prz += 65536; pgn += 65536;
    } else { rzC = rzB; gnC0 = gnB0; gnC1 = gnB1; }

    const f16* hrd = (t & 1) ? hB : hA;   // static under unroll-2

    // phase A: gh = h @ W_hh^T (96 MFMA, all operands in regs; A via broadcast)
    f32x4 acc[12];
    {
      const f16x8 af0 = *(const f16x8*)&hrd[0];
#pragma unroll
      for (int i = 0; i < 12; i++)
        acc[i] = __builtin_amdgcn_mfma_f32_16x16x32_f16(af0, wf[i >> 2][i & 3][0], zs, 0, 0, 0);
    }
#pragma unroll
    for (int ks = 1; ks < 8; ks++) {
      const f16x8 af = *(const f16x8*)&hrd[ks * 32];
#pragma unroll
      for (int i = 0; i < 12; i++)
        acc[i] = __builtin_amdgcn_mfma_f32_16x16x32_f16(af, wf[i >> 2][i & 3][ks], acc[i], 0, 0, 0);
    }

    // wave-local redistribution: lanes 0-15 hold batch rows 0,1 in regs 0,1
    if (lane < 16) {
#pragma unroll
      for (int g = 0; g < 3; g++)
#pragma unroll
        for (int j = 0; j < 4; j++) {
          float2 v; v.x = acc[g * 4 + j][0]; v.y = acc[g * 4 + j][1];
          *(float2*)&gh_l[w][g][j * 16 + lane][0] = v;
        }
    }
    __builtin_amdgcn_sched_barrier(0);
    asm volatile("s_waitcnt lgkmcnt(0)" ::: "memory");
    __builtin_amdgcn_sched_barrier(0);

    const float2 ghr = *(const float2*)&gh_l[w][0][lane][0];
    const float2 ghz = *(const float2*)&gh_l[w][1][lane][0];
    const float2 ghn = *(const float2*)&gh_l[w][2][lane][0];

    // phase B: 2 h-outputs per lane (batch rows 0,1 at this col)
    H2U u0; u0.u = rzA.x;
    H2U u1; u1.u = rzA.y;
    const float rr0 = sigm((float)u0.h[0] + ghr.x);
    const float zz0 = sigm((float)u0.h[1] + ghz.x);
    const float nn0 = tanh_f((float)gnA0 + rr0 * (ghn.x + bhhn));
    const float ho0 = nn0 + zz0 * (hr0 - nn0);
    const float rr1 = sigm((float)u1.h[0] + ghr.y);
    const float zz1 = sigm((float)u1.h[1] + ghz.y);
    const float nn1 = tanh_f((float)gnA1 + rr1 * (ghn.y + bhhn));
    const float ho1 = nn1 + zz1 * (hr1 - nn1);

    pst[0] = (f16)ho0; pst[256] = (f16)ho1; pst += 65536;  // outs
    const float2 dn = *(const float2*)&done_l[t][0];        // masks into t+1
    hr0 = (dn.x != 0.f) ? 0.f : ho0;
    hr1 = (dn.y != 0.f) ? 0.f : ho1;
    const int nxt = (t & 1) ^ 1;
    h2[nxt][0][col] = (f16)hr0;
    h2[nxt][1][col] = (f16)hr1;

    rzA = rzB; gnA0 = gnB0; gnA1 = gnB1;
    rzB = rzC; gnB0 = gnC0; gnB1 = gnC1;
    __syncthreads();
  }
}

// ---------------------------------------------------------------------------
// K4: heads. M-tile 64, N=32 (16 pol + 1 val + pad), grid 2048, block 256.
// ---------------------------------------------------------------------------
__global__ __launch_bounds__(256) void k_heads(const f16* __restrict__ outs,
                                               const f16* __restrict__ headW_h,
                                               const float* __restrict__ pol_b,
                                               const float* __restrict__ val_b,
                                               float* __restrict__ out) {
  __shared__ f16 lA[64 * 256];  // 32KB swizzled
  __shared__ f16 lB[32 * 256];  // 16KB
  const int tid = threadIdx.x, lane = tid & 63, w = tid >> 6;
  const int m0 = blockIdx.x * 64;
#pragma unroll
  for (int i = 0; i < 8; i++) {
    int c = tid + i * 256;
    int r = c >> 5, o = (c & 31) * 8;
    f16x8 v = *(const f16x8*)(outs + (size_t)(m0 + r) * H_DIM + o);
    uint32_t off = ((uint32_t)(r * 512 + o * 2)) ^ (((uint32_t)(r & 7)) << 4);
    *(f16x8*)((char*)lA + off) = v;
  }
#pragma unroll
  for (int i = 0; i < 4; i++) {
    int c = tid + i * 256;
    int r = c >> 5, o = (c & 31) * 8;
    f16x8 v = *(const f16x8*)(headW_h + (size_t)r * H_DIM + o);
    uint32_t off = ((uint32_t)(r * 512 + o * 2)) ^ (((uint32_t)(r & 7)) << 4);
    *(f16x8*)((char*)lB + off) = v;
  }
  __syncthreads();
  f32x4 acc[2];
  acc[0] = fz4(); acc[1] = fz4();
#pragma unroll
  for (int ks = 0; ks < 8; ks++) {
    const int ar = w * 16 + (lane & 15);
    const int kofs = (ks * 32 + ((lane >> 4) << 3)) * 2;
    uint32_t aoff = ((uint32_t)(ar * 512 + kofs)) ^ (((uint32_t)(ar & 7)) << 4);
    f16x8 af = *(const f16x8*)((char*)lA + aoff);
#pragma unroll
    for (int nt = 0; nt < 2; nt++) {
      const int br = nt * 16 + (lane & 15);
      uint32_t boff = ((uint32_t)(br * 512 + kofs)) ^ (((uint32_t)(br & 7)) << 4);
      f16x8 bfr = *(const f16x8*)((char*)lB + boff);
      acc[nt] = __builtin_amdgcn_mfma_f32_16x16x32_f16(af, bfr, acc[nt], 0, 0, 0);
    }
  }
  const int n = lane & 15;
  const float pb = pol_b[n];
  const float vb = val_b[0];
#pragma unroll
  for (int r = 0; r < 4; r++) {
    const int mrow = m0 + w * 16 + ((lane >> 4) << 2) + r;
    out[(size_t)mrow * 16 + n] = acc[0][r] + pb;
    if (n == 0) out[(size_t)TB * 16 + mrow] = acc[1][r] + vb;
  }
}

// ---------------------------------------------------------------------------
// Workspace layout (192.5 MiB total):
//   [0,128Mi)        gi_rz f16 [TB][256][2]  (r,z interleaved)
//   [128Mi,192Mi)    xgi  f16 [TB][256]  (x -> gi_n -> outs, race-free)
//   [192Mi,+475KB)   encW_h | Wih_h | headW_h
// ---------------------------------------------------------------------------
extern "C" void kernel_launch(void* const* d_in, const int* in_sizes, int n_in,
                              void* d_out, int out_size, void* d_ws, size_t ws_size,
                              hipStream_t stream) {
  (void)in_sizes; (void)n_in; (void)out_size; (void)ws_size;
  const float* obs   = (const float*)d_in[0];
  const float* done  = (const float*)d_in[1];
  const float* encW  = (const float*)d_in[2];
  const float* enc_b = (const float*)d_in[3];
  const float* Wih   = (const float*)d_in[4];
  const float* Whh   = (const float*)d_in[5];
  const float* b_ih  = (const float*)d_in[6];
  const float* b_hh  = (const float*)d_in[7];
  const float* polW  = (const float*)d_in[8];
  const float* pol_b = (const float*)d_in[9];
  const float* valW  = (const float*)d_in[10];
  const float* val_b = (const float*)d_in[11];

  char* ws = (char*)d_ws;
  f16* gi_rz   = (f16*)ws;
  f16* xgi     = (f16*)(ws + (size_t)134217728);
  f16* encW_h  = (f16*)(ws + (size_t)201326592);
  f16* Wih_h   = encW_h + 32768;
  f16* headW_h = Wih_h + 196608;
  float* outp  = (float*)d_out;

  k_prep<<<dim3(928), dim3(256), 0, stream>>>(encW, Wih, polW, valW, encW_h, Wih_h, headW_h);
  k_enc<<<dim3(1024), dim3(512), 0, stream>>>(obs, encW_h, enc_b, xgi);
  k_gi3<<<dim3(2048), dim3(512), 0, stream>>>(xgi, Wih_h, b_ih, b_hh, gi_rz, xgi);
  k_scan<<<dim3(128), dim3(256), 0, stream>>>(Whh, b_hh, done, (const uint32_t*)gi_rz, xgi);
  k_heads<<<dim3(2048), dim3(256), 0, stream>>>(xgi, headW_h, pol_b, val_b, outp);
}

// Round 7
// 842.392 us; speedup vs baseline: 1.2358x; 1.2358x over previous
//
#include <hip/hip_runtime.h>
#include <stdint.h>

#define T_DIM 512
#define B_DIM 256
#define OBS_DIM 128
#define H_DIM 256
#define TB (T_DIM * B_DIM)

typedef _Float16 f16;
typedef __attribute__((ext_vector_type(8))) _Float16 f16x8;
typedef __attribute__((ext_vector_type(4))) float f32x4;

union H2U { f16 h[2]; uint32_t u; };

__device__ __forceinline__ f32x4 fz4() { f32x4 v; v[0]=0.f; v[1]=0.f; v[2]=0.f; v[3]=0.f; return v; }
__device__ __forceinline__ float sigm(float x) {
  float e = __expf(-x);
  return __builtin_amdgcn_rcpf(1.f + e);
}
__device__ __forceinline__ float tanh_f(float x) {
  float e = __expf(-2.f * x);
  return (1.f - e) * __builtin_amdgcn_rcpf(1.f + e);
}

// ---------------------------------------------------------------------------
// K0: weights -> f16. encW 32768 | Wih 196608 | head 8192 (rows0-15 pol,16 val)
// ---------------------------------------------------------------------------
__global__ void k_prep(const float* __restrict__ encW, const float* __restrict__ Wih,
                       const float* __restrict__ polW, const float* __restrict__ valW,
                       f16* __restrict__ encW_h, f16* __restrict__ Wih_h,
                       f16* __restrict__ headW_h) {
  int e = blockIdx.x * 256 + threadIdx.x;
  if (e < 32768) { encW_h[e] = (f16)encW[e]; return; }
  e -= 32768;
  if (e < 196608) { Wih_h[e] = (f16)Wih[e]; return; }
  e -= 196608;
  if (e < 8192) {
    int r = e >> 8, c = e & 255;
    float v = (r < 16) ? polW[r * 256 + c] : (r == 16 ? valW[c] : 0.f);
    headW_h[e] = (f16)v;
  }
}

// ---------------------------------------------------------------------------
// K1: x = tanh(obs @ enc_W^T + enc_b) -> f16 into xgi. M-tile 128, grid 1024.
// ---------------------------------------------------------------------------
__global__ __launch_bounds__(512) void k_enc(const float* __restrict__ obs,
                                             const f16* __restrict__ encW_h,
                                             const float* __restrict__ enc_b,
                                             f16* __restrict__ xgi) {
  __shared__ f16 lA[128 * 64];  // 16KB [128 rows][64 k] swizzled
  __shared__ f16 lB[256 * 64];  // 32KB [256 n][64 k] swizzled
  const int tid = threadIdx.x, lane = tid & 63, w = tid >> 6;
  const int m0 = blockIdx.x * 128;
  f32x4 acc[16];
#pragma unroll
  for (int i = 0; i < 16; i++) acc[i] = fz4();

  for (int kc = 0; kc < 2; kc++) {
    const int k0c = kc * 64;
#pragma unroll
    for (int i = 0; i < 4; i++) {
      int c = tid + i * 512;
      int r = c >> 4, kk = (c & 15) * 4;
      float4 v = *(const float4*)(obs + (size_t)(m0 + r) * OBS_DIM + k0c + kk);
      H2U a, b;
      a.h[0] = (f16)v.x; a.h[1] = (f16)v.y; b.h[0] = (f16)v.z; b.h[1] = (f16)v.w;
      uint32_t off = ((uint32_t)(r * 128 + kk * 2)) ^ (((uint32_t)(r & 7)) << 4);
      uint2 p; p.x = a.u; p.y = b.u;
      *(uint2*)((char*)lA + off) = p;
    }
#pragma unroll
    for (int i = 0; i < 4; i++) {
      int c = tid + i * 512;
      int r = c >> 3, kk = (c & 7) * 8;
      f16x8 v = *(const f16x8*)(encW_h + (size_t)r * OBS_DIM + k0c + kk);
      uint32_t off = ((uint32_t)(r * 128 + kk * 2)) ^ (((uint32_t)(r & 7)) << 4);
      *(f16x8*)((char*)lB + off) = v;
    }
    __syncthreads();
#pragma unroll
    for (int ks = 0; ks < 2; ks++) {
      const int ar = w * 16 + (lane & 15);
      const int kofs = (ks * 32 + ((lane >> 4) << 3)) * 2;
      uint32_t aoff = ((uint32_t)(ar * 128 + kofs)) ^ (((uint32_t)(ar & 7)) << 4);
      f16x8 af = *(const f16x8*)((char*)lA + aoff);
#pragma unroll
      for (int i = 0; i < 16; i++) {
        const int br = i * 16 + (lane & 15);
        uint32_t boff = ((uint32_t)(br * 128 + kofs)) ^ (((uint32_t)(br & 7)) << 4);
        f16x8 bfr = *(const f16x8*)((char*)lB + boff);
        acc[i] = __builtin_amdgcn_mfma_f32_16x16x32_f16(af, bfr, acc[i], 0, 0, 0);
      }
    }
    __syncthreads();
  }
  const int mrow = m0 + w * 16 + ((lane >> 4) << 2);
#pragma unroll
  for (int i = 0; i < 16; i++) {
    const int col = i * 16 + (lane & 15);
    const float bb = enc_b[col];
#pragma unroll
    for (int r = 0; r < 4; r++) {
      float s = acc[i][r] + bb;
      xgi[(size_t)(mrow + r) * H_DIM + col] = (f16)tanh_f(s);
    }
  }
}

// ---------------------------------------------------------------------------
// K2: all 3 gates fused: gi = x @ W_ih^T + bias. M-tile 64, N=768, grid 2048.
// bias: b_ih + b_hh for r,z cols (<512); b_ih only for n.
// r,z -> gi_rz f16 [TB][256][2] INTERLEAVED; n -> xgi [TB][256].
// ---------------------------------------------------------------------------
__global__ __launch_bounds__(512) void k_gi3(const f16* __restrict__ xgi_r,
                                             const f16* __restrict__ Wih_h,
                                             const float* __restrict__ b_ih,
                                             const float* __restrict__ b_hh,
                                             f16* __restrict__ gi_rz,
                                             f16* __restrict__ xgi_w) {
  __shared__ f16 lA[64 * 64];    // 8KB
  __shared__ f16 lB[768 * 64];   // 96KB
  const int tid = threadIdx.x, lane = tid & 63, w = tid >> 6;
  const int m0 = blockIdx.x * 64;
  const int mstrip = w >> 1, nh = w & 1;
  f32x4 acc[24];
#pragma unroll
  for (int i = 0; i < 24; i++) acc[i] = fz4();

  for (int kc = 0; kc < 4; kc++) {
    const int k0c = kc * 64;
    {
      int r = tid >> 3, kk = (tid & 7) * 8;
      f16x8 v = *(const f16x8*)(xgi_r + (size_t)(m0 + r) * H_DIM + k0c + kk);
      uint32_t off = ((uint32_t)(r * 128 + kk * 2)) ^ (((uint32_t)(r & 7)) << 4);
      *(f16x8*)((char*)lA + off) = v;
    }
#pragma unroll
    for (int i = 0; i < 12; i++) {
      int c = tid + i * 512;
      int r = c >> 3, kk = (c & 7) * 8;
      f16x8 v = *(const f16x8*)(Wih_h + (size_t)r * H_DIM + k0c + kk);
      uint32_t off = ((uint32_t)(r * 128 + kk * 2)) ^ (((uint32_t)(r & 7)) << 4);
      *(f16x8*)((char*)lB + off) = v;
    }
    __syncthreads();
#pragma unroll
    for (int ks = 0; ks < 2; ks++) {
      const int ar = mstrip * 16 + (lane & 15);
      const int kofs = (ks * 32 + ((lane >> 4) << 3)) * 2;
      uint32_t aoff = ((uint32_t)(ar * 128 + kofs)) ^ (((uint32_t)(ar & 7)) << 4);
      f16x8 af = *(const f16x8*)((char*)lA + aoff);
#pragma unroll
      for (int i = 0; i < 24; i++) {
        const int br = nh * 384 + i * 16 + (lane & 15);
        uint32_t boff = ((uint32_t)(br * 128 + kofs)) ^ (((uint32_t)(br & 7)) << 4);
        f16x8 bfr = *(const f16x8*)((char*)lB + boff);
        acc[i] = __builtin_amdgcn_mfma_f32_16x16x32_f16(af, bfr, acc[i], 0, 0, 0);
      }
    }
    __syncthreads();
  }
  const int mrow = m0 + mstrip * 16 + ((lane >> 4) << 2);
#pragma unroll
  for (int i = 0; i < 24; i++) {
    const int col = nh * 384 + i * 16 + (lane & 15);
    float bb = b_ih[col];
    if (col < 512) bb += b_hh[col];
#pragma unroll
    for (int r = 0; r < 4; r++) {
      float s = acc[i][r] + bb;
      size_t tb = (size_t)(mrow + r);
      if (col < 512) gi_rz[tb * 512 + (size_t)((col & 255) * 2 + (col >> 8))] = (f16)s;
      else           xgi_w[tb * 256 + (col - 512)] = (f16)s;
    }
  }
}

// ---------------------------------------------------------------------------
// K3: GRU scan v7 = v5 structure + RAW per-step barrier.
// grid(128) x block 512 (8 waves, 2/SIMD), WG owns 2 batch rows.
// KEY CHANGE vs v5: per-step __syncthreads() (which drains vmcnt(0), i.e.
// waits for next-step gi HBM prefetch + outs store to COMPLETE every step)
// is replaced by s_waitcnt lgkmcnt(0) + raw s_barrier. LDS hand-off only
// needs lgkmcnt; gi loads keep compiler-inserted vmcnt waits at their
// consumption point one step later (latency actually hidden now).
// ---------------------------------------------------------------------------
__global__ __launch_bounds__(512, 2) void k_scan(const float* __restrict__ Whh,
                                                 const float* __restrict__ b_hh,
                                                 const float* __restrict__ done,
                                                 const uint32_t* __restrict__ gi_rz,
                                                 f16* xgi) {
  __shared__ f16 h_l[2][16][264];      // 16.5KB double-buffered, rows 2-15 stay 0
  __shared__ float gh_l[8][6][16][2];  // 6KB [wave][g*2+hh][col&15][row]
  __shared__ float done_l[T_DIM][2];   // 4KB
  __shared__ f16 wb_l[8 * 12 * 64 * 8];  // 96KB [w][i2j][lane][8] ks 6,7 frags
  const int tid = threadIdx.x, lane = tid & 63, w = tid >> 6;
  const int b0 = blockIdx.x * 2;

  for (int i = tid; i < 2 * 16 * 264; i += 512) ((f16*)h_l)[i] = (f16)0.f;
  {
    float2 dv = *(const float2*)(done + (size_t)tid * B_DIM + b0);
    done_l[tid][0] = dv.x; done_l[tid][1] = dv.y;
  }

  // W_hh -> f16 B-frags: ks 0-5 in registers, ks 6-7 into LDS (lane-contig)
  f16x8 wf[6][6];
#pragma unroll
  for (int g = 0; g < 3; g++) {
#pragma unroll
    for (int hh = 0; hh < 2; hh++) {
      const int i6 = g * 2 + hh;
      const int rowW = g * 256 + w * 32 + hh * 16 + (lane & 15);
      const float* wrow = Whh + (size_t)rowW * H_DIM;
#pragma unroll
      for (int ks = 0; ks < 8; ks++) {
        const int k0 = ks * 32 + ((lane >> 4) << 3);
        float4 a = *(const float4*)(wrow + k0);
        float4 b = *(const float4*)(wrow + k0 + 4);
        f16x8 f;
        f[0] = (f16)a.x; f[1] = (f16)a.y; f[2] = (f16)a.z; f[3] = (f16)a.w;
        f[4] = (f16)b.x; f[5] = (f16)b.y; f[6] = (f16)b.z; f[7] = (f16)b.w;
        if (ks < 6) wf[i6][ks] = f;
        else *(f16x8*)&wb_l[((w * 12 + i6 * 2 + (ks - 6)) * 64 + lane) * 8] = f;
      }
    }
  }
  // persistent C-in seeds: zero for r,z (bias folded in gi); bhh_n for n gate
  f32x4 zs = fz4();
  f32x4 ns0, ns1;
  {
    const float bv0 = b_hh[512 + w * 32 + (lane & 15)];
    const float bv1 = b_hh[512 + w * 32 + 16 + (lane & 15)];
    ns0[0] = bv0; ns0[1] = bv0; ns0[2] = bv0; ns0[3] = bv0;
    ns1[0] = bv1; ns1[1] = bv1; ns1[2] = bv1; ns1[3] = bv1;
  }

  const int row = lane >> 5, c = lane & 31, col = (w << 5) + c;
  const size_t base = ((size_t)b0 + row) * 256 + col;
  const uint32_t* prz = gi_rz + base;
  const f16* pgn = xgi + base;
  f16* pst = xgi + base;
  uint32_t rz_nx = *prz;
  f16 gn_nx = *pgn;
  float hreg = 0.f;

  const f16* hrd0 = &h_l[0][lane & 15][(lane >> 4) << 3];
  const f16* wrd = &wb_l[(w * 12 * 64 + lane) * 8];
  __syncthreads();

  for (int t = 0; t < T_DIM; t++) {
    const uint32_t rz_cu = rz_nx;
    const f16 gn_cu = gn_nx;
    if (t != T_DIM - 1) { prz += 65536; pgn += 65536; rz_nx = *prz; gn_nx = *pgn; }
    const int cur = t & 1;
    const f16* hrd = hrd0 + cur * (16 * 264);

    f32x4 acc[6];
    __builtin_amdgcn_s_setprio(1);
    {
      const f16x8 af0 = *(const f16x8*)&hrd[0];
      acc[0] = __builtin_amdgcn_mfma_f32_16x16x32_f16(af0, wf[0][0], zs, 0, 0, 0);
      acc[1] = __builtin_amdgcn_mfma_f32_16x16x32_f16(af0, wf[1][0], zs, 0, 0, 0);
      acc[2] = __builtin_amdgcn_mfma_f32_16x16x32_f16(af0, wf[2][0], zs, 0, 0, 0);
      acc[3] = __builtin_amdgcn_mfma_f32_16x16x32_f16(af0, wf[3][0], zs, 0, 0, 0);
      acc[4] = __builtin_amdgcn_mfma_f32_16x16x32_f16(af0, wf[4][0], ns0, 0, 0, 0);
      acc[5] = __builtin_amdgcn_mfma_f32_16x16x32_f16(af0, wf[5][0], ns1, 0, 0, 0);
    }
#pragma unroll
    for (int ks = 1; ks < 6; ks++) {
      const f16x8 af = *(const f16x8*)&hrd[ks * 32];
#pragma unroll
      for (int i = 0; i < 6; i++)
        acc[i] = __builtin_amdgcn_mfma_f32_16x16x32_f16(af, wf[i][ks], acc[i], 0, 0, 0);
    }
#pragma unroll
    for (int j = 0; j < 2; j++) {
      const f16x8 af = *(const f16x8*)&hrd[(6 + j) * 32];
#pragma unroll
      for (int i = 0; i < 6; i++) {
        const f16x8 bf = *(const f16x8*)&wrd[(i * 2 + j) * 512];
        acc[i] = __builtin_amdgcn_mfma_f32_16x16x32_f16(af, bf, acc[i], 0, 0, 0);
      }
    }
    __builtin_amdgcn_s_setprio(0);

    // wave-local gh redistribution (lanes 0-15 hold batch rows 0,1 in regs 0,1)
    if (lane < 16) {
#pragma unroll
      for (int i = 0; i < 6; i++) {
        float2 v; v.x = acc[i][0]; v.y = acc[i][1];
        *(float2*)&gh_l[w][i][lane][0] = v;
      }
    }
    __builtin_amdgcn_sched_barrier(0);
    asm volatile("s_waitcnt lgkmcnt(0)" ::: "memory");
    __builtin_amdgcn_sched_barrier(0);
    const int hh = c >> 4, cl = c & 15;
    const float ghr = gh_l[w][0 + hh][cl][row];
    const float ghz = gh_l[w][2 + hh][cl][row];
    const float ghn = gh_l[w][4 + hh][cl][row];
    H2U u; u.u = rz_cu;
    const float rr = sigm((float)u.h[0] + ghr);
    const float zz = sigm((float)u.h[1] + ghz);
    const float nn = tanh_f((float)gn_cu + rr * ghn);
    const float ho = nn + zz * (hreg - nn);
    *pst = (f16)ho; pst += 65536;                 // outs (same addr as gn slot)
    const float dn = done_l[t][row];              // masks h going into t+1
    hreg = (dn != 0.f) ? 0.f : ho;
    h_l[cur ^ 1][row][col] = (f16)hreg;

    // RAW barrier: drain LDS only (NOT vmcnt) then s_barrier.
    __builtin_amdgcn_sched_barrier(0);
    asm volatile("s_waitcnt lgkmcnt(0)" ::: "memory");
    __builtin_amdgcn_s_barrier();
    __builtin_amdgcn_sched_barrier(0);
  }
}

// ---------------------------------------------------------------------------
// K4: heads. M-tile 64, N=32 (16 pol + 1 val + pad), grid 2048, block 256.
// ---------------------------------------------------------------------------
__global__ __launch_bounds__(256) void k_heads(const f16* __restrict__ outs,
                                               const f16* __restrict__ headW_h,
                                               const float* __restrict__ pol_b,
                                               const float* __restrict__ val_b,
                                               float* __restrict__ out) {
  __shared__ f16 lA[64 * 256];  // 32KB swizzled
  __shared__ f16 lB[32 * 256];  // 16KB
  const int tid = threadIdx.x, lane = tid & 63, w = tid >> 6;
  const int m0 = blockIdx.x * 64;
#pragma unroll
  for (int i = 0; i < 8; i++) {
    int c = tid + i * 256;
    int r = c >> 5, o = (c & 31) * 8;
    f16x8 v = *(const f16x8*)(outs + (size_t)(m0 + r) * H_DIM + o);
    uint32_t off = ((uint32_t)(r * 512 + o * 2)) ^ (((uint32_t)(r & 7)) << 4);
    *(f16x8*)((char*)lA + off) = v;
  }
#pragma unroll
  for (int i = 0; i < 4; i++) {
    int c = tid + i * 256;
    int r = c >> 5, o = (c & 31) * 8;
    f16x8 v = *(const f16x8*)(headW_h + (size_t)r * H_DIM + o);
    uint32_t off = ((uint32_t)(r * 512 + o * 2)) ^ (((uint32_t)(r & 7)) << 4);
    *(f16x8*)((char*)lB + off) = v;
  }
  __syncthreads();
  f32x4 acc[2];
  acc[0] = fz4(); acc[1] = fz4();
#pragma unroll
  for (int ks = 0; ks < 8; ks++) {
    const int ar = w * 16 + (lane & 15);
    const int kofs = (ks * 32 + ((lane >> 4) << 3)) * 2;
    uint32_t aoff = ((uint32_t)(ar * 512 + kofs)) ^ (((uint32_t)(ar & 7)) << 4);
    f16x8 af = *(const f16x8*)((char*)lA + aoff);
#pragma unroll
    for (int nt = 0; nt < 2; nt++) {
      const int br = nt * 16 + (lane & 15);
      uint32_t boff = ((uint32_t)(br * 512 + kofs)) ^ (((uint32_t)(br & 7)) << 4);
      f16x8 bfr = *(const f16x8*)((char*)lB + boff);
      acc[nt] = __builtin_amdgcn_mfma_f32_16x16x32_f16(af, bfr, acc[nt], 0, 0, 0);
    }
  }
  const int n = lane & 15;
  const float pb = pol_b[n];
  const float vb = val_b[0];
#pragma unroll
  for (int r = 0; r < 4; r++) {
    const int mrow = m0 + w * 16 + ((lane >> 4) << 2) + r;
    out[(size_t)mrow * 16 + n] = acc[0][r] + pb;
    if (n == 0) out[(size_t)TB * 16 + mrow] = acc[1][r] + vb;
  }
}

// ---------------------------------------------------------------------------
// Workspace layout (192.5 MiB total):
//   [0,128Mi)        gi_rz f16 [TB][256][2]  (r,z interleaved)
//   [128Mi,192Mi)    xgi  f16 [TB][256]  (x -> gi_n -> outs, race-free)
//   [192Mi,+475KB)   encW_h | Wih_h | headW_h
// ---------------------------------------------------------------------------
extern "C" void kernel_launch(void* const* d_in, const int* in_sizes, int n_in,
                              void* d_out, int out_size, void* d_ws, size_t ws_size,
                              hipStream_t stream) {
  (void)in_sizes; (void)n_in; (void)out_size; (void)ws_size;
  const float* obs   = (const float*)d_in[0];
  const float* done  = (const float*)d_in[1];
  const float* encW  = (const float*)d_in[2];
  const float* enc_b = (const float*)d_in[3];
  const float* Wih   = (const float*)d_in[4];
  const float* Whh   = (const float*)d_in[5];
  const float* b_ih  = (const float*)d_in[6];
  const float* b_hh  = (const float*)d_in[7];
  const float* polW  = (const float*)d_in[8];
  const float* pol_b = (const float*)d_in[9];
  const float* valW  = (const float*)d_in[10];
  const float* val_b = (const float*)d_in[11];

  char* ws = (char*)d_ws;
  f16* gi_rz   = (f16*)ws;
  f16* xgi     = (f16*)(ws + (size_t)134217728);
  f16* encW_h  = (f16*)(ws + (size_t)201326592);
  f16* Wih_h   = encW_h + 32768;
  f16* headW_h = Wih_h + 196608;
  float* outp  = (float*)d_out;

  k_prep<<<dim3(928), dim3(256), 0, stream>>>(encW, Wih, polW, valW, encW_h, Wih_h, headW_h);
  k_enc<<<dim3(1024), dim3(512), 0, stream>>>(obs, encW_h, enc_b, xgi);
  k_gi3<<<dim3(2048), dim3(512), 0, stream>>>(xgi, Wih_h, b_ih, b_hh, gi_rz, xgi);
  k_scan<<<dim3(128), dim3(512), 0, stream>>>(Whh, b_hh, done, (const uint32_t*)gi_rz, xgi);
  k_heads<<<dim3(2048), dim3(256), 0, stream>>>(xgi, headW_h, pol_b, val_b, outp);
}